// Round 1
// 2738.720 us; speedup vs baseline: 1.0509x; 1.0509x over previous
//
#include <hip/hip_runtime.h>
#include <hip/hip_bf16.h>

#define NT 512
typedef unsigned short u16;

__device__ __forceinline__ u16 tobf(float x) {
  union { __hip_bfloat16 h; u16 u; } cv;
  cv.h = __float2bfloat16(x);
  return cv.u;
}
__device__ __forceinline__ float frombf(u16 u) {
  return __uint_as_float(((unsigned)u) << 16);
}
__device__ __forceinline__ float sigf(float x) {
  return __builtin_amdgcn_rcpf(1.f + __builtin_amdgcn_exp2f(-1.4426950408889634f * x));
}
__device__ __forceinline__ float tanh_fast(float x) {
  return 1.f - 2.f * __builtin_amdgcn_rcpf(1.f + __builtin_amdgcn_exp2f(2.8853900817779268f * x));
}

struct SeqArgs {
  const float* input;
  const float* nv1_0; const float* nv2_0; const float* nv1_1; const float* nv2_1;
  const float* w_start0; const float* b_start0; const float* w_mlp0; const float* b_mlp0;
  const float* w_end0;   const float* b_end0;   const float* w_lin0; const float* b_lin0;
  const float* gamma0;   const float* beta0;
  const float* w_start1; const float* b_start1; const float* w_mlp1; const float* b_mlp1;
  const float* w_end1;   const float* b_end1;   const float* w_lin1; const float* b_lin1;
  const float* gamma1;   const float* beta1;
  float* HCOL;   // ws ring [32][192][192] fp32
  int*   flags;  // ws [192*32] ints, stride 32 (128B) per row
  float* out_all; float* out_hrow; float* out_hcol;
};

// NT=512: 8 waves = 2 waves/SIMD co-resident (latency hiding). launch_bounds(512,2)
// caps VGPR at 256 so both waves fit per SIMD.
__global__ __launch_bounds__(NT, 2) void seq_kernel(SeqArgs A) {
  const int n = blockIdx.x, w = n >> 3, b = n & 7, tid = threadIdx.x;
  const int pred = (n + 184) % 192;   // n-8 mod 192

  __shared__ __align__(16) float sCIN[768];     // [h_row | h_col | x(<=2ch)]
  __shared__ __align__(16) u16   sWS[64 * 132]; // conv weights bf16, row=ich*16+c
  __shared__ __align__(16) float sAT[4096];     // aT[w*64+v]
  __shared__ __align__(16) float sH[2][1024];   // [c*64+v]
  __shared__ __align__(16) float sAbuf[4928];
  float* const sPart = sAbuf;          // [0..3071] pre-conv partials (P*16*64)
  float* const sG    = sAbuf;          // [0..2047] (32x64, stride-1 scalar access)
  float* const sE    = sAbuf + 2048;   // [2048..2431]
  float* const sY    = sAbuf;          // [0..1151]
  float* const smWE  = sAbuf + 3072;   // 192
  float* const smBE  = sAbuf + 3264;   // 6
  float* const smWM  = sAbuf + 3328;   // 32*50 (stride 50: bank-conflict-free)

  for (int layer = 0; layer < 2; ++layer) {
    const int in_dim = 3 + layer;
    const int P = in_dim - 1;  // pre channels: h_row + x-channels
    const float* nv1    = layer ? A.nv1_1    : A.nv1_0;
    const float* nv2    = layer ? A.nv2_1    : A.nv2_0;
    const float* wstart = layer ? A.w_start1 : A.w_start0;
    const float* bs     = layer ? A.b_start1 : A.b_start0;
    const float* wm     = layer ? A.w_mlp1   : A.w_mlp0;
    const float* bm     = layer ? A.b_mlp1   : A.b_mlp0;
    const float* we     = layer ? A.w_end1   : A.w_end0;
    const float* be     = layer ? A.b_end1   : A.b_end0;
    const float* wl     = layer ? A.w_lin1   : A.w_lin0;
    const float* bl     = layer ? A.b_lin1   : A.b_lin0;
    const float* gm     = layer ? A.gamma1   : A.gamma0;
    const float* bt     = layer ? A.beta1    : A.beta0;

    // ---- layer init: adjacency (scores -> softmax -> sAT), weights, regs ----
    for (int idx = tid; idx < 4096; idx += NT) {
      int v = idx >> 6, ww = idx & 63;
      float s = 0.f;
      for (int j = 0; j < 40; ++j) s = fmaf(nv1[v*40 + j], nv2[j*64 + ww], s);
      sAbuf[idx] = fmaxf(s, 0.f);
    }
    __syncthreads();
    if (tid < 64) {
      const int v = tid;
      float m = -1e30f;
      for (int ww = 0; ww < 64; ++ww) m = fmaxf(m, sAbuf[v*64 + ww]);
      float s = 0.f;
      for (int ww = 0; ww < 64; ++ww) { float e = expf(sAbuf[v*64 + ww] - m); sAbuf[v*64 + ww] = e; s += e; }
      float inv = 1.f / s, rs = 1.f;
      for (int ww = 0; ww < 64; ++ww) rs += sAbuf[v*64 + ww] * inv;
      float irs = 1.f / rs;
      for (int ww = 0; ww < 64; ++ww) {
        float a = sAbuf[v*64 + ww] * inv + ((ww == v) ? 1.f : 0.f);
        sAT[ww*64 + v] = a * irs;
      }
    }
    __syncthreads();  // sAT ready; scores region dead
    for (int idx = tid; idx < 16*in_dim*132; idx += NT) {
      int row = idx / 132, k = idx - row*132;
      sWS[idx] = (k < 129) ? tobf(wstart[((row & 15)*in_dim + (row >> 4))*129 + k]) : (u16)0;
    }
    for (int idx = tid; idx < 1536; idx += NT) { int o = idx/48, c = idx - o*48; smWM[o*50 + c] = wm[idx]; }
    for (int idx = tid; idx < 192; idx += NT) smWE[idx] = we[idx];
    if (tid < 6) smBE[tid] = be[tid];
    for (int d = tid; d < 384; d += NT) sCIN[d] = 0.f;

    const int v_p = tid & 63;
    const int o0  = tid >> 6;         // wave id, 0..7
    const float bmv0 = bm[o0], bmv1 = bm[o0 + 8], bmv2 = bm[o0 + 16], bmv3 = bm[o0 + 24];
    float blv = 0.f, gmv = 1.f, btv = 0.f;
    if (tid < 384) blv = bl[(tid >= 192) ? tid - 192 : tid];
    if (tid < 192) { gmv = gm[tid]; btv = bt[tid]; }
    float bs_r[2];
    bs_r[0] = bs[tid >> 6];
    bs_r[1] = bs[(tid >> 6) + 8];
    __syncthreads();

    // ---- pre-phase: stage x(t), conv of {h_row, x} channels, assemble h0pre ----
    auto pre_phase = [&](int t) {
      if (layer == 0) {
        int o = t - w;
        if (o >= 0 && o < 48) {
          const float* xr = A.input + (((size_t)(b*24 + w)*48 + o)*192);
          for (int d = tid; d < 192; d += NT) sCIN[384 + d] = xr[d];
        } else {
          for (int d = tid; d < 192; d += NT) sCIN[384 + d] = 0.f;
        }
      } else {
        const float* xr = A.out_all + ((size_t)n*71 + t)*384;
        for (int d = tid; d < 384; d += NT) sCIN[384 + d] = xr[d];
      }
      __syncthreads();
      // slot = cidx*16 + vg; cidx = p*16+c; 4 outputs per slot (sliding window).
      // P=2: 512 slots (1/thread). P=3: 768 slots (waves 0-3 take a 2nd slot).
      const int nslots = P << 8;
      for (int s = tid; s < nslots; s += NT) {
        const int cidx = s >> 4;
        const int p = cidx >> 4, c = cidx & 15;
        const int vg = s & 15;
        const int ich = (p == 0) ? 0 : (p + 1);
        const float* xin = ((p == 0) ? &sCIN[0] : &sCIN[384 + (p-1)*192]) + vg*4;
        const u16* wrow = &sWS[(ich*16 + c)*132];
        float a0 = 0.f, a1 = 0.f, a2 = 0.f, a3 = 0.f;
        float4 xc = *(const float4*)xin;
        for (int k4 = 0; k4 < 128; k4 += 4) {
          ushort4 wu = *(const ushort4*)(wrow + k4);
          float w0 = frombf(wu.x), w1 = frombf(wu.y), w2 = frombf(wu.z), w3 = frombf(wu.w);
          float4 xn = *(const float4*)(xin + k4 + 4);
          a0 = fmaf(w3, xc.w, fmaf(w2, xc.z, fmaf(w1, xc.y, fmaf(w0, xc.x, a0))));
          a1 = fmaf(w3, xn.x, fmaf(w2, xc.w, fmaf(w1, xc.z, fmaf(w0, xc.y, a1))));
          a2 = fmaf(w3, xn.y, fmaf(w2, xn.x, fmaf(w1, xc.w, fmaf(w0, xc.z, a2))));
          a3 = fmaf(w3, xn.z, fmaf(w2, xn.y, fmaf(w1, xn.x, fmaf(w0, xc.w, a3))));
          xc = xn;
        }
        float wk = frombf(wrow[128]);
        a0 = fmaf(wk, xc.x, a0); a1 = fmaf(wk, xc.y, a1);
        a2 = fmaf(wk, xc.z, a2); a3 = fmaf(wk, xc.w, a3);
        *(float4*)&sPart[cidx*64 + vg*4] = make_float4(a0, a1, a2, a3);
      }
      __syncthreads();
      {
        const int c0 = tid >> 6, v = tid & 63;   // each thread: (c0,v) and (c0+8,v)
        float sum0 = bs_r[0], sum1 = bs_r[1];
        for (int p = 0; p < P; ++p) {
          sum0 += sPart[(p*16 + c0     )*64 + v];
          sum1 += sPart[(p*16 + c0 + 8 )*64 + v];
        }
        sH[0][ c0      *64 + v] = sum0;
        sH[0][(c0 + 8 )*64 + v] = sum1;
      }
      __syncthreads();
    };
    pre_phase(0);

    for (int t = 0; t < 71; ++t) {
      const int S = layer*71 + t;

      // ---- dependent path ----
      if (t > 0) {
        if (tid == 0) {
          while (__hip_atomic_load(&A.flags[pred*32], __ATOMIC_ACQUIRE, __HIP_MEMORY_SCOPE_AGENT) < S)
            __builtin_amdgcn_s_sleep(1);
        }
        __syncthreads();  // B1
        float* hc = A.HCOL + ((size_t)((S-1) & 31)*192 + pred)*192;
        for (int d = tid; d < 192; d += NT)
          sCIN[192 + d] = __hip_atomic_load(&hc[d], __ATOMIC_RELAXED, __HIP_MEMORY_SCOPE_AGENT);
        __syncthreads();  // B2
      }

      // h_col conv, in-place accumulate into sH[0]; 2 outputs/thread, all 512
      {
        const int c = tid >> 5, vg2 = tid & 31;
        const int vbase = c*64 + vg2*2;
        const float* xin = &sCIN[192 + vg2*2];
        const u16* wrow = &sWS[(16 + c)*132];
        float a0 = sH[0][vbase], a1 = sH[0][vbase + 1];
        float2 xc = *(const float2*)xin;
        for (int k2 = 0; k2 < 128; k2 += 2) {
          ushort2 wu = *(const ushort2*)(wrow + k2);
          float w0 = frombf(wu.x), w1 = frombf(wu.y);
          float2 xn = *(const float2*)(xin + k2 + 2);
          a0 = fmaf(w1, xc.y, fmaf(w0, xc.x, a0));
          a1 = fmaf(w1, xn.x, fmaf(w0, xc.y, a1));
          xc = xn;
        }
        float wk = frombf(wrow[128]);
        a0 = fmaf(wk, xc.x, a0); a1 = fmaf(wk, xc.y, a1);
        sH[0][vbase] = a0; sH[0][vbase + 1] = a1;
      }
      __syncthreads();  // B3

      float g0 = bmv0, g1 = bmv1, g2 = bmv2, g3 = bmv3;
      // (e) h1 = 0.05 h0 + 0.95 (h0 @ aT); G += wm[:,0:16] h0
      {
        const int c0 = o0 * 2;   // this wave's 2 rows
        float pa0 = 0.f, pa1 = 0.f;
        for (int w4 = 0; w4 < 64; w4 += 4) {
          float a0v = sAT[(w4+0)*64 + v_p];
          float a1v = sAT[(w4+1)*64 + v_p];
          float a2v = sAT[(w4+2)*64 + v_p];
          float a3v = sAT[(w4+3)*64 + v_p];
          float4 h0v = *(const float4*)&sH[0][ c0      *64 + w4];
          float4 h1v = *(const float4*)&sH[0][(c0 + 1 )*64 + w4];
          pa0 = fmaf(h0v.x, a0v, pa0); pa0 = fmaf(h0v.y, a1v, pa0);
          pa0 = fmaf(h0v.z, a2v, pa0); pa0 = fmaf(h0v.w, a3v, pa0);
          pa1 = fmaf(h1v.x, a0v, pa1); pa1 = fmaf(h1v.y, a1v, pa1);
          pa1 = fmaf(h1v.z, a2v, pa1); pa1 = fmaf(h1v.w, a3v, pa1);
        }
        sH[1][ c0      *64 + v_p] = fmaf(0.95f, pa0, 0.05f * sH[0][ c0      *64 + v_p]);
        sH[1][(c0 + 1 )*64 + v_p] = fmaf(0.95f, pa1, 0.05f * sH[0][(c0 + 1 )*64 + v_p]);
        for (int c = 0; c < 16; ++c) {
          float hv = sH[0][c*64 + v_p];
          g0 = fmaf(smWM[(o0     )*50 + c], hv, g0);
          g1 = fmaf(smWM[(o0 +  8)*50 + c], hv, g1);
          g2 = fmaf(smWM[(o0 + 16)*50 + c], hv, g2);
          g3 = fmaf(smWM[(o0 + 24)*50 + c], hv, g3);
        }
      }
      __syncthreads();  // B4

      // (f) h2 = 0.05 h0 + 0.95 (h1 @ aT) in place; G += wm[:,16:32] h1
      {
        const int c0 = o0 * 2;
        float pa0 = 0.f, pa1 = 0.f;
        for (int w4 = 0; w4 < 64; w4 += 4) {
          float a0v = sAT[(w4+0)*64 + v_p];
          float a1v = sAT[(w4+1)*64 + v_p];
          float a2v = sAT[(w4+2)*64 + v_p];
          float a3v = sAT[(w4+3)*64 + v_p];
          float4 h0v = *(const float4*)&sH[1][ c0      *64 + w4];
          float4 h1v = *(const float4*)&sH[1][(c0 + 1 )*64 + w4];
          pa0 = fmaf(h0v.x, a0v, pa0); pa0 = fmaf(h0v.y, a1v, pa0);
          pa0 = fmaf(h0v.z, a2v, pa0); pa0 = fmaf(h0v.w, a3v, pa0);
          pa1 = fmaf(h1v.x, a0v, pa1); pa1 = fmaf(h1v.y, a1v, pa1);
          pa1 = fmaf(h1v.z, a2v, pa1); pa1 = fmaf(h1v.w, a3v, pa1);
        }
        float h00 = sH[0][ c0      *64 + v_p];
        float h01 = sH[0][(c0 + 1 )*64 + v_p];
        sH[0][ c0      *64 + v_p] = fmaf(0.95f, pa0, 0.05f * h00);
        sH[0][(c0 + 1 )*64 + v_p] = fmaf(0.95f, pa1, 0.05f * h01);
        for (int c = 0; c < 16; ++c) {
          float hv = sH[1][c*64 + v_p];
          g0 = fmaf(smWM[(o0     )*50 + 16 + c], hv, g0);
          g1 = fmaf(smWM[(o0 +  8)*50 + 16 + c], hv, g1);
          g2 = fmaf(smWM[(o0 + 16)*50 + 16 + c], hv, g2);
          g3 = fmaf(smWM[(o0 + 24)*50 + 16 + c], hv, g3);
        }
      }
      __syncthreads();  // B5

      // (g) G += wm[:,32:48] h2; exact GELU; -> sG (stride-1 scalar stores)
      {
        for (int c = 0; c < 16; ++c) {
          float hv = sH[0][c*64 + v_p];
          g0 = fmaf(smWM[(o0     )*50 + 32 + c], hv, g0);
          g1 = fmaf(smWM[(o0 +  8)*50 + 32 + c], hv, g1);
          g2 = fmaf(smWM[(o0 + 16)*50 + 32 + c], hv, g2);
          g3 = fmaf(smWM[(o0 + 24)*50 + 32 + c], hv, g3);
        }
        g0 = 0.5f * g0 * (1.f + erff(g0 * 0.70710678118654752f));
        g1 = 0.5f * g1 * (1.f + erff(g1 * 0.70710678118654752f));
        g2 = 0.5f * g2 * (1.f + erff(g2 * 0.70710678118654752f));
        g3 = 0.5f * g3 * (1.f + erff(g3 * 0.70710678118654752f));
        sG[(o0     )*64 + v_p] = g0;
        sG[(o0 +  8)*64 + v_p] = g1;
        sG[(o0 + 16)*64 + v_p] = g2;
        sG[(o0 + 24)*64 + v_p] = g3;
      }
      __syncthreads();  // B6

      // (h) E = be + we @ G
      for (int idx = tid; idx < 384; idx += NT) {
        int o2 = idx >> 6, v = idx & 63;
        float acc = smBE[o2];
        for (int c = 0; c < 32; ++c) acc = fmaf(smWE[o2*32 + c], sG[c*64 + v], acc);
        sE[idx] = acc;
      }
      __syncthreads();  // B7

      // (i) Y = bl + E @ wl^T : 384 threads, 3 rows each
      if (tid < 384) {
        const int d  = (tid >= 192) ? tid - 192 : tid;
        const int r0 = (tid >= 192) ? 3 : 0;
        const float4* wrow = (const float4*)(wl + d*64);
        float y0 = blv, y1 = blv, y2 = blv;
        for (int q = 0; q < 16; ++q) {
          float4 wv = wrow[q];
          float4 e0 = *(const float4*)&sE[(r0+0)*64 + q*4];
          float4 e1 = *(const float4*)&sE[(r0+1)*64 + q*4];
          float4 e2 = *(const float4*)&sE[(r0+2)*64 + q*4];
          y0 = fmaf(e0.x,wv.x, fmaf(e0.y,wv.y, fmaf(e0.z,wv.z, fmaf(e0.w,wv.w, y0))));
          y1 = fmaf(e1.x,wv.x, fmaf(e1.y,wv.y, fmaf(e1.z,wv.z, fmaf(e1.w,wv.w, y1))));
          y2 = fmaf(e2.x,wv.x, fmaf(e2.y,wv.y, fmaf(e2.z,wv.z, fmaf(e2.w,wv.w, y2))));
        }
        sY[(r0+0)*192 + d] = y0;
        sY[(r0+1)*192 + d] = y1;
        sY[(r0+2)*192 + d] = y2;
      }
      __syncthreads();  // B8

      // (j1) LN stats -> sH[1][0..13]
      if (tid < 192) {
        const int r = tid >> 5, l32 = tid & 31;
        float sm = 0.f, sq = 0.f;
#pragma unroll
        for (int m = 0; m < 6; ++m) {
          float v = sY[r*192 + l32 + 32*m];
          sm += v; sq = fmaf(v, v, sq);
        }
#pragma unroll
        for (int off = 16; off >= 1; off >>= 1) {
          sm += __shfl_xor(sm, off);
          sq += __shfl_xor(sq, off);
        }
        if (l32 == 0) {
          float mu = sm * (1.f/192.f);
          float var = sq * (1.f/192.f) - mu*mu;
          sH[1][r] = mu;
          sH[1][8 + r] = rsqrtf(fmaxf(var, 0.f) + 1e-5f);
        }
      }
      __syncthreads();  // B9

      float hcn = 0.f;
      // (k1) col gates -> hcn -> HCOL
      if (tid < 192) {
        const int d = tid;
        float y2 = fmaf((sY[2*192+d] - sH[1][2]) * sH[1][10], gmv, btv);
        float y3 = fmaf((sY[3*192+d] - sH[1][3]) * sH[1][11], gmv, btv);
        float y5 = fmaf((sY[5*192+d] - sH[1][5]) * sH[1][13], gmv, btv);
        float ugc = sigf(y2), ogc = sigf(y3), igc = tanh_fast(y5);
        float hc = sCIN[192 + d];
        hcn = tanh_fast(fmaf(ugc, igc, (1.f - ugc)*hc)) * ogc;
        __hip_atomic_store(&A.HCOL[((size_t)(S & 31)*192 + n)*192 + d], hcn,
                           __ATOMIC_RELAXED, __HIP_MEMORY_SCOPE_AGENT);
      }
      __syncthreads();  // B10
      if (tid == 0) {
        __threadfence();
        __hip_atomic_store(&A.flags[n*32], S + 1, __ATOMIC_RELEASE, __HIP_MEMORY_SCOPE_AGENT);
      }
      // (k2) row gates + outputs (off critical path)
      if (tid < 192) {
        const int d = tid;
        float y0 = fmaf((sY[0*192+d] - sH[1][0]) * sH[1][8],  gmv, btv);
        float y1 = fmaf((sY[1*192+d] - sH[1][1]) * sH[1][9],  gmv, btv);
        float y4 = fmaf((sY[4*192+d] - sH[1][4]) * sH[1][12], gmv, btv);
        float ugr = sigf(y0), ogr = sigf(y1), igr = tanh_fast(y4);
        float hr = sCIN[d];
        float hrn = tanh_fast(fmaf(ugr, igr, (1.f - ugr)*hr)) * ogr;
        sCIN[d] = hrn;
        float* oa = A.out_all + ((size_t)n*71 + t)*384;
        if (layer == 0) { oa[d] = hrn; oa[192 + d] = hcn; }
        else           { oa[d] = hrn + sCIN[384 + d]; oa[192 + d] = hcn + sCIN[576 + d]; }
        if (t == 47 + w)
          A.out_hrow[(((size_t)b*2 + layer)*24 + w)*192 + d] = hrn;
        if (w == 23 && t >= 23)
          A.out_hcol[(((size_t)b*2 + layer)*48 + (t - 23))*192 + d] = hcn;
      }
      __syncthreads();  // B11
      if (t < 70) pre_phase(t + 1);
    } // t
    __syncthreads();
  } // layer
}

extern "C" void kernel_launch(void* const* d_in, const int* in_sizes, int n_in,
                              void* d_out, int out_size, void* d_ws, size_t ws_size,
                              hipStream_t stream) {
  (void)in_sizes; (void)n_in; (void)out_size; (void)ws_size;
  char* ws = (char*)d_ws;
  int*   flags = (int*)ws;                 // 24,576 B (192 x 128B)
  float* HCOL  = (float*)(ws + 24576);     // 4,718,592 B
  // total ws: 4,743,168 B

  hipMemsetAsync(flags, 0, 24576, stream);

  SeqArgs A;
  A.input    = (const float*)d_in[0];
  A.nv1_0    = (const float*)d_in[1];  A.nv2_0 = (const float*)d_in[2];
  A.w_start0 = (const float*)d_in[3];  A.b_start0 = (const float*)d_in[4];
  A.w_mlp0   = (const float*)d_in[5];  A.b_mlp0   = (const float*)d_in[6];
  A.w_end0   = (const float*)d_in[7];  A.b_end0   = (const float*)d_in[8];
  A.w_lin0   = (const float*)d_in[9];  A.b_lin0   = (const float*)d_in[10];
  A.gamma0   = (const float*)d_in[11]; A.beta0    = (const float*)d_in[12];
  A.nv1_1    = (const float*)d_in[13]; A.nv2_1 = (const float*)d_in[14];
  A.w_start1 = (const float*)d_in[15]; A.b_start1 = (const float*)d_in[16];
  A.w_mlp1   = (const float*)d_in[17]; A.b_mlp1   = (const float*)d_in[18];
  A.w_end1   = (const float*)d_in[19]; A.b_end1   = (const float*)d_in[20];
  A.w_lin1   = (const float*)d_in[21]; A.b_lin1   = (const float*)d_in[22];
  A.gamma1   = (const float*)d_in[23]; A.beta1    = (const float*)d_in[24];
  A.HCOL = HCOL; A.flags = flags;
  A.out_all  = (float*)d_out;
  A.out_hrow = (float*)d_out + 5234688;
  A.out_hcol = (float*)d_out + 5308416;

  seq_kernel<<<192, NT, 0, stream>>>(A);
}

// Round 2
// 2707.288 us; speedup vs baseline: 1.0631x; 1.0116x over previous
//
#include <hip/hip_runtime.h>
#include <hip/hip_bf16.h>

#define NT 512
typedef unsigned short u16;

__device__ __forceinline__ u16 tobf(float x) {
  union { __hip_bfloat16 h; u16 u; } cv;
  cv.h = __float2bfloat16(x);
  return cv.u;
}
__device__ __forceinline__ float frombf(u16 u) {
  return __uint_as_float(((unsigned)u) << 16);
}
__device__ __forceinline__ float sigf(float x) {
  return __builtin_amdgcn_rcpf(1.f + __builtin_amdgcn_exp2f(-1.4426950408889634f * x));
}
__device__ __forceinline__ float tanh_fast(float x) {
  return 1.f - 2.f * __builtin_amdgcn_rcpf(1.f + __builtin_amdgcn_exp2f(2.8853900817779268f * x));
}
// wave-local LDS ordering: waits this wave's ds ops, blocks compiler motion.
__device__ __forceinline__ void lds_fence() {
  asm volatile("s_waitcnt lgkmcnt(0)" ::: "memory");
  __builtin_amdgcn_sched_barrier(0);
}

struct SeqArgs {
  const float* input;
  const float* nv1_0; const float* nv2_0; const float* nv1_1; const float* nv2_1;
  const float* w_start0; const float* b_start0; const float* w_mlp0; const float* b_mlp0;
  const float* w_end0;   const float* b_end0;   const float* w_lin0; const float* b_lin0;
  const float* gamma0;   const float* beta0;
  const float* w_start1; const float* b_start1; const float* w_mlp1; const float* b_mlp1;
  const float* w_end1;   const float* b_end1;   const float* w_lin1; const float* b_lin1;
  const float* gamma1;   const float* beta1;
  float* HCOL;   // ws ring [32][192][192] fp32
  int*   flags;  // ws [192*32] ints, stride 32 (128B) per row
  float* out_all; float* out_hrow; float* out_hcol;
};

__global__ __launch_bounds__(NT, 2) void seq_kernel(SeqArgs A) {
  const int n = blockIdx.x, w = n >> 3, b = n & 7, tid = threadIdx.x;
  const int pred = (n + 184) % 192;   // n-8 mod 192

  __shared__ __align__(16) float sCIN[768];     // [h_row | h_col | x(<=2ch)]
  __shared__ __align__(16) u16   sWS[64 * 132]; // conv weights bf16, row=ich*16+c
  __shared__ __align__(16) float sAT[4096];     // aT[w*64+v]
  __shared__ __align__(16) float sH[2][1024];   // h0 / h1 rows [c*64+v]
  __shared__ __align__(16) float sAbuf[4928];
  float* const sPart = sAbuf;          // [0..3071] pre-conv partials (P*16*64)
  float* const sG    = sAbuf;          // [0..2047]
  float* const sH2c  = sAbuf + 2048;   // [2048..3071] h2 rows (dead after G)
  float* const sE    = sAbuf + 2048;   // [2048..2431] (overwrites dead h2)
  float* const sY    = sAbuf;          // [0..1151]   (overwrites dead sG)
  float* const smWE  = sAbuf + 3072;   // 192
  float* const smBE  = sAbuf + 3264;   // 6
  float* const smWM  = sAbuf + 3328;   // 32*50 (stride 50: bank-conflict-free)

  for (int layer = 0; layer < 2; ++layer) {
    const int in_dim = 3 + layer;
    const int P = in_dim - 1;  // pre channels: h_row + x-channels
    const float* nv1    = layer ? A.nv1_1    : A.nv1_0;
    const float* nv2    = layer ? A.nv2_1    : A.nv2_0;
    const float* wstart = layer ? A.w_start1 : A.w_start0;
    const float* bs     = layer ? A.b_start1 : A.b_start0;
    const float* wm     = layer ? A.w_mlp1   : A.w_mlp0;
    const float* bm     = layer ? A.b_mlp1   : A.b_mlp0;
    const float* we     = layer ? A.w_end1   : A.w_end0;
    const float* be     = layer ? A.b_end1   : A.b_end0;
    const float* wl     = layer ? A.w_lin1   : A.w_lin0;
    const float* bl     = layer ? A.b_lin1   : A.b_lin0;
    const float* gm     = layer ? A.gamma1   : A.gamma0;
    const float* bt     = layer ? A.beta1    : A.beta0;

    // ---- layer init: adjacency (scores -> softmax -> sAT), weights, regs ----
    for (int idx = tid; idx < 4096; idx += NT) {
      int v = idx >> 6, ww = idx & 63;
      float s = 0.f;
      for (int j = 0; j < 40; ++j) s = fmaf(nv1[v*40 + j], nv2[j*64 + ww], s);
      sAbuf[idx] = fmaxf(s, 0.f);
    }
    __syncthreads();
    if (tid < 64) {
      const int v = tid;
      float m = -1e30f;
      for (int ww = 0; ww < 64; ++ww) m = fmaxf(m, sAbuf[v*64 + ww]);
      float s = 0.f;
      for (int ww = 0; ww < 64; ++ww) { float e = expf(sAbuf[v*64 + ww] - m); sAbuf[v*64 + ww] = e; s += e; }
      float inv = 1.f / s, rs = 1.f;
      for (int ww = 0; ww < 64; ++ww) rs += sAbuf[v*64 + ww] * inv;
      float irs = 1.f / rs;
      for (int ww = 0; ww < 64; ++ww) {
        float a = sAbuf[v*64 + ww] * inv + ((ww == v) ? 1.f : 0.f);
        sAT[ww*64 + v] = a * irs;
      }
    }
    __syncthreads();  // sAT ready; scores region dead
    for (int idx = tid; idx < 16*in_dim*132; idx += NT) {
      int row = idx / 132, k = idx - row*132;
      sWS[idx] = (k < 129) ? tobf(wstart[((row & 15)*in_dim + (row >> 4))*129 + k]) : (u16)0;
    }
    for (int idx = tid; idx < 1536; idx += NT) { int o = idx/48, c = idx - o*48; smWM[o*50 + c] = wm[idx]; }
    for (int idx = tid; idx < 192; idx += NT) smWE[idx] = we[idx];
    if (tid < 6) smBE[tid] = be[tid];
    for (int d = tid; d < 384; d += NT) sCIN[d] = 0.f;

    const int v_p = tid & 63;
    const int o0  = tid >> 6;         // wave id, 0..7
    const float bmv0 = bm[o0], bmv1 = bm[o0 + 8], bmv2 = bm[o0 + 16], bmv3 = bm[o0 + 24];
    float blv = 0.f, gmv = 1.f, btv = 0.f;
    if (tid < 384) blv = bl[(tid >= 192) ? tid - 192 : tid];
    if (tid < 192) { gmv = gm[tid]; btv = bt[tid]; }
    float bs_r[2];
    bs_r[0] = bs[tid >> 6];
    bs_r[1] = bs[(tid >> 6) + 8];
    __syncthreads();

    // ---- pre-phase: stage x(t), conv of {h_row, x} channels, assemble h0pre ----
    auto pre_phase = [&](int t) {
      if (layer == 0) {
        int o = t - w;
        if (o >= 0 && o < 48) {
          const float* xr = A.input + (((size_t)(b*24 + w)*48 + o)*192);
          for (int d = tid; d < 192; d += NT) sCIN[384 + d] = xr[d];
        } else {
          for (int d = tid; d < 192; d += NT) sCIN[384 + d] = 0.f;
        }
      } else {
        const float* xr = A.out_all + ((size_t)n*71 + t)*384;
        for (int d = tid; d < 384; d += NT) sCIN[384 + d] = xr[d];
      }
      __syncthreads();
      const int nslots = P << 8;
      for (int s = tid; s < nslots; s += NT) {
        const int cidx = s >> 4;
        const int p = cidx >> 4, c = cidx & 15;
        const int vg = s & 15;
        const int ich = (p == 0) ? 0 : (p + 1);
        const float* xin = ((p == 0) ? &sCIN[0] : &sCIN[384 + (p-1)*192]) + vg*4;
        const u16* wrow = &sWS[(ich*16 + c)*132];
        float a0 = 0.f, a1 = 0.f, a2 = 0.f, a3 = 0.f;
        float4 xc = *(const float4*)xin;
        for (int k4 = 0; k4 < 128; k4 += 4) {
          ushort4 wu = *(const ushort4*)(wrow + k4);
          float w0 = frombf(wu.x), w1 = frombf(wu.y), w2 = frombf(wu.z), w3 = frombf(wu.w);
          float4 xn = *(const float4*)(xin + k4 + 4);
          a0 = fmaf(w3, xc.w, fmaf(w2, xc.z, fmaf(w1, xc.y, fmaf(w0, xc.x, a0))));
          a1 = fmaf(w3, xn.x, fmaf(w2, xc.w, fmaf(w1, xc.z, fmaf(w0, xc.y, a1))));
          a2 = fmaf(w3, xn.y, fmaf(w2, xn.x, fmaf(w1, xc.w, fmaf(w0, xc.z, a2))));
          a3 = fmaf(w3, xn.z, fmaf(w2, xn.y, fmaf(w1, xn.x, fmaf(w0, xc.w, a3))));
          xc = xn;
        }
        float wk = frombf(wrow[128]);
        a0 = fmaf(wk, xc.x, a0); a1 = fmaf(wk, xc.y, a1);
        a2 = fmaf(wk, xc.z, a2); a3 = fmaf(wk, xc.w, a3);
        *(float4*)&sPart[cidx*64 + vg*4] = make_float4(a0, a1, a2, a3);
      }
      __syncthreads();
      {
        const int c0 = tid >> 6, v = tid & 63;
        float sum0 = bs_r[0], sum1 = bs_r[1];
        for (int p = 0; p < P; ++p) {
          sum0 += sPart[(p*16 + c0     )*64 + v];
          sum1 += sPart[(p*16 + c0 + 8 )*64 + v];
        }
        sH[0][ c0      *64 + v] = sum0;
        sH[0][(c0 + 8 )*64 + v] = sum1;
      }
      __syncthreads();
    };
    pre_phase(0);

    for (int t = 0; t < 71; ++t) {
      const int S = layer*71 + t;

      // ---- dependent path: merged poll + hc load (no acquire -> no L2 inv) ----
      if (t > 0) {
        if (tid < 192) {
          while (__hip_atomic_load(&A.flags[pred*32], __ATOMIC_RELAXED, __HIP_MEMORY_SCOPE_AGENT) < S)
            __builtin_amdgcn_s_sleep(1);
          __builtin_amdgcn_sched_barrier(0);
          asm volatile("" ::: "memory");
          const float* hc = A.HCOL + ((size_t)((S-1) & 31)*192 + pred)*192;
          sCIN[192 + tid] = __hip_atomic_load(&hc[tid], __ATOMIC_RELAXED, __HIP_MEMORY_SCOPE_AGENT);
        }
        __syncthreads();  // Bp
      }

      // ---- phase A (wave-local, no block barriers): h_col conv -> prop1 -> prop2
      {
        // conv: wave w owns rows {2w, 2w+1}; 2 outputs/thread
        const int c = tid >> 5, vg2 = tid & 31;
        const int vbase = c*64 + vg2*2;
        const float* xin = &sCIN[192 + vg2*2];
        const u16* wrow = &sWS[(16 + c)*132];
        float a0 = sH[0][vbase], a1 = sH[0][vbase + 1];
        float2 xc = *(const float2*)xin;
        for (int k2 = 0; k2 < 128; k2 += 2) {
          ushort2 wu = *(const ushort2*)(wrow + k2);
          float w0 = frombf(wu.x), w1 = frombf(wu.y);
          float2 xn = *(const float2*)(xin + k2 + 2);
          a0 = fmaf(w1, xc.y, fmaf(w0, xc.x, a0));
          a1 = fmaf(w1, xn.x, fmaf(w0, xc.y, a1));
          xc = xn;
        }
        float wk = frombf(wrow[128]);
        a0 = fmaf(wk, xc.x, a0); a1 = fmaf(wk, xc.y, a1);
        sH[0][vbase] = a0; sH[0][vbase + 1] = a1;
      }
      lds_fence();
      {
        const int c0 = o0 * 2;   // this wave's 2 rows
        // prop1: h1 = 0.05 h0 + 0.95 (h0 @ aT), wave-local rows
        float pa0 = 0.f, pa1 = 0.f;
        for (int w4 = 0; w4 < 64; w4 += 4) {
          float a0v = sAT[(w4+0)*64 + v_p];
          float a1v = sAT[(w4+1)*64 + v_p];
          float a2v = sAT[(w4+2)*64 + v_p];
          float a3v = sAT[(w4+3)*64 + v_p];
          float4 h0v = *(const float4*)&sH[0][ c0      *64 + w4];
          float4 h1v = *(const float4*)&sH[0][(c0 + 1 )*64 + w4];
          pa0 = fmaf(h0v.x, a0v, pa0); pa0 = fmaf(h0v.y, a1v, pa0);
          pa0 = fmaf(h0v.z, a2v, pa0); pa0 = fmaf(h0v.w, a3v, pa0);
          pa1 = fmaf(h1v.x, a0v, pa1); pa1 = fmaf(h1v.y, a1v, pa1);
          pa1 = fmaf(h1v.z, a2v, pa1); pa1 = fmaf(h1v.w, a3v, pa1);
        }
        float h0a = sH[0][ c0      *64 + v_p];
        float h0b = sH[0][(c0 + 1 )*64 + v_p];
        sH[1][ c0      *64 + v_p] = fmaf(0.95f, pa0, 0.05f * h0a);
        sH[1][(c0 + 1 )*64 + v_p] = fmaf(0.95f, pa1, 0.05f * h0b);
        lds_fence();
        // prop2: h2 = 0.05 h0 + 0.95 (h1 @ aT) -> sH2c
        float pb0 = 0.f, pb1 = 0.f;
        for (int w4 = 0; w4 < 64; w4 += 4) {
          float a0v = sAT[(w4+0)*64 + v_p];
          float a1v = sAT[(w4+1)*64 + v_p];
          float a2v = sAT[(w4+2)*64 + v_p];
          float a3v = sAT[(w4+3)*64 + v_p];
          float4 h0v = *(const float4*)&sH[1][ c0      *64 + w4];
          float4 h1v = *(const float4*)&sH[1][(c0 + 1 )*64 + w4];
          pb0 = fmaf(h0v.x, a0v, pb0); pb0 = fmaf(h0v.y, a1v, pb0);
          pb0 = fmaf(h0v.z, a2v, pb0); pb0 = fmaf(h0v.w, a3v, pb0);
          pb1 = fmaf(h1v.x, a0v, pb1); pb1 = fmaf(h1v.y, a1v, pb1);
          pb1 = fmaf(h1v.z, a2v, pb1); pb1 = fmaf(h1v.w, a3v, pb1);
        }
        sH2c[ c0      *64 + v_p] = fmaf(0.95f, pb0, 0.05f * h0a);
        sH2c[(c0 + 1 )*64 + v_p] = fmaf(0.95f, pb1, 0.05f * h0b);
      }
      __syncthreads();  // B3: h0/h1/h2 all ready

      // (g) G = bm + wm0 h0 + wm1 h1 + wm2 h2; exact GELU -> sG
      {
        float g0 = bmv0, g1 = bmv1, g2 = bmv2, g3 = bmv3;
#pragma unroll
        for (int c = 0; c < 16; ++c) {
          float h0v = sH[0][c*64 + v_p];
          float h1v = sH[1][c*64 + v_p];
          float h2v = sH2c[c*64 + v_p];
          g0 = fmaf(smWM[(o0     )*50 + c], h0v, fmaf(smWM[(o0     )*50 + 16 + c], h1v, fmaf(smWM[(o0     )*50 + 32 + c], h2v, g0)));
          g1 = fmaf(smWM[(o0 +  8)*50 + c], h0v, fmaf(smWM[(o0 +  8)*50 + 16 + c], h1v, fmaf(smWM[(o0 +  8)*50 + 32 + c], h2v, g1)));
          g2 = fmaf(smWM[(o0 + 16)*50 + c], h0v, fmaf(smWM[(o0 + 16)*50 + 16 + c], h1v, fmaf(smWM[(o0 + 16)*50 + 32 + c], h2v, g2)));
          g3 = fmaf(smWM[(o0 + 24)*50 + c], h0v, fmaf(smWM[(o0 + 24)*50 + 16 + c], h1v, fmaf(smWM[(o0 + 24)*50 + 32 + c], h2v, g3)));
        }
        g0 = 0.5f * g0 * (1.f + erff(g0 * 0.70710678118654752f));
        g1 = 0.5f * g1 * (1.f + erff(g1 * 0.70710678118654752f));
        g2 = 0.5f * g2 * (1.f + erff(g2 * 0.70710678118654752f));
        g3 = 0.5f * g3 * (1.f + erff(g3 * 0.70710678118654752f));
        sG[(o0     )*64 + v_p] = g0;
        sG[(o0 +  8)*64 + v_p] = g1;
        sG[(o0 + 16)*64 + v_p] = g2;
        sG[(o0 + 24)*64 + v_p] = g3;
      }
      __syncthreads();  // B4 (also: h2 region now dead -> sE may overwrite)

      // (h) E = be + we @ G
      for (int idx = tid; idx < 384; idx += NT) {
        int o2 = idx >> 6, v = idx & 63;
        float acc = smBE[o2];
        for (int c = 0; c < 32; ++c) acc = fmaf(smWE[o2*32 + c], sG[c*64 + v], acc);
        sE[idx] = acc;
      }
      __syncthreads();  // B5

      // (i) Y = bl + E @ wl^T : 384 threads, 3 rows each
      if (tid < 384) {
        const int d  = (tid >= 192) ? tid - 192 : tid;
        const int r0 = (tid >= 192) ? 3 : 0;
        const float4* wrow = (const float4*)(wl + d*64);
        float y0 = blv, y1 = blv, y2 = blv;
        for (int q = 0; q < 16; ++q) {
          float4 wv = wrow[q];
          float4 e0 = *(const float4*)&sE[(r0+0)*64 + q*4];
          float4 e1 = *(const float4*)&sE[(r0+1)*64 + q*4];
          float4 e2 = *(const float4*)&sE[(r0+2)*64 + q*4];
          y0 = fmaf(e0.x,wv.x, fmaf(e0.y,wv.y, fmaf(e0.z,wv.z, fmaf(e0.w,wv.w, y0))));
          y1 = fmaf(e1.x,wv.x, fmaf(e1.y,wv.y, fmaf(e1.z,wv.z, fmaf(e1.w,wv.w, y1))));
          y2 = fmaf(e2.x,wv.x, fmaf(e2.y,wv.y, fmaf(e2.z,wv.z, fmaf(e2.w,wv.w, y2))));
        }
        sY[(r0+0)*192 + d] = y0;
        sY[(r0+1)*192 + d] = y1;
        sY[(r0+2)*192 + d] = y2;
      }
      __syncthreads();  // B6

      // (j1) LN stats -> sH[1][0..13]
      if (tid < 192) {
        const int r = tid >> 5, l32 = tid & 31;
        float sm = 0.f, sq = 0.f;
#pragma unroll
        for (int m = 0; m < 6; ++m) {
          float v = sY[r*192 + l32 + 32*m];
          sm += v; sq = fmaf(v, v, sq);
        }
#pragma unroll
        for (int off = 16; off >= 1; off >>= 1) {
          sm += __shfl_xor(sm, off);
          sq += __shfl_xor(sq, off);
        }
        if (l32 == 0) {
          float mu = sm * (1.f/192.f);
          float var = sq * (1.f/192.f) - mu*mu;
          sH[1][r] = mu;
          sH[1][8 + r] = rsqrtf(fmaxf(var, 0.f) + 1e-5f);
        }
      }
      __syncthreads();  // B7

      float hcn = 0.f;
      // (k1) col gates -> hcn -> HCOL (sc1 agent stores reach coherence point)
      if (tid < 192) {
        const int d = tid;
        float y2 = fmaf((sY[2*192+d] - sH[1][2]) * sH[1][10], gmv, btv);
        float y3 = fmaf((sY[3*192+d] - sH[1][3]) * sH[1][11], gmv, btv);
        float y5 = fmaf((sY[5*192+d] - sH[1][5]) * sH[1][13], gmv, btv);
        float ugc = sigf(y2), ogc = sigf(y3), igc = tanh_fast(y5);
        float hc = sCIN[192 + d];
        hcn = tanh_fast(fmaf(ugc, igc, (1.f - ugc)*hc)) * ogc;
        __hip_atomic_store(&A.HCOL[((size_t)(S & 31)*192 + n)*192 + d], hcn,
                           __ATOMIC_RELAXED, __HIP_MEMORY_SCOPE_AGENT);
      }
      __syncthreads();  // B8: every wave's stores drained (vmcnt(0)) at barrier entry
      if (tid == 0) {
        asm volatile("s_waitcnt vmcnt(0)" ::: "memory");
        __hip_atomic_store(&A.flags[n*32], S + 1, __ATOMIC_RELAXED, __HIP_MEMORY_SCOPE_AGENT);
      }
      // (k2) row gates + outputs (off critical path)
      if (tid < 192) {
        const int d = tid;
        float y0 = fmaf((sY[0*192+d] - sH[1][0]) * sH[1][8],  gmv, btv);
        float y1 = fmaf((sY[1*192+d] - sH[1][1]) * sH[1][9],  gmv, btv);
        float y4 = fmaf((sY[4*192+d] - sH[1][4]) * sH[1][12], gmv, btv);
        float ugr = sigf(y0), ogr = sigf(y1), igr = tanh_fast(y4);
        float hr = sCIN[d];
        float hrn = tanh_fast(fmaf(ugr, igr, (1.f - ugr)*hr)) * ogr;
        sCIN[d] = hrn;
        float* oa = A.out_all + ((size_t)n*71 + t)*384;
        if (layer == 0) { oa[d] = hrn; oa[192 + d] = hcn; }
        else           { oa[d] = hrn + sCIN[384 + d]; oa[192 + d] = hcn + sCIN[576 + d]; }
        if (t == 47 + w)
          A.out_hrow[(((size_t)b*2 + layer)*24 + w)*192 + d] = hrn;
        if (w == 23 && t >= 23)
          A.out_hcol[(((size_t)b*2 + layer)*48 + (t - 23))*192 + d] = hcn;
      }
      __syncthreads();  // B9
      if (t < 70) pre_phase(t + 1);
    } // t
    __syncthreads();
  } // layer
}

extern "C" void kernel_launch(void* const* d_in, const int* in_sizes, int n_in,
                              void* d_out, int out_size, void* d_ws, size_t ws_size,
                              hipStream_t stream) {
  (void)in_sizes; (void)n_in; (void)out_size; (void)ws_size;
  char* ws = (char*)d_ws;
  int*   flags = (int*)ws;                 // 24,576 B (192 x 128B)
  float* HCOL  = (float*)(ws + 24576);     // 4,718,592 B
  // total ws: 4,743,168 B

  hipMemsetAsync(flags, 0, 24576, stream);

  SeqArgs A;
  A.input    = (const float*)d_in[0];
  A.nv1_0    = (const float*)d_in[1];  A.nv2_0 = (const float*)d_in[2];
  A.w_start0 = (const float*)d_in[3];  A.b_start0 = (const float*)d_in[4];
  A.w_mlp0   = (const float*)d_in[5];  A.b_mlp0   = (const float*)d_in[6];
  A.w_end0   = (const float*)d_in[7];  A.b_end0   = (const float*)d_in[8];
  A.w_lin0   = (const float*)d_in[9];  A.b_lin0   = (const float*)d_in[10];
  A.gamma0   = (const float*)d_in[11]; A.beta0    = (const float*)d_in[12];
  A.nv1_1    = (const float*)d_in[13]; A.nv2_1 = (const float*)d_in[14];
  A.w_start1 = (const float*)d_in[15]; A.b_start1 = (const float*)d_in[16];
  A.w_mlp1   = (const float*)d_in[17]; A.b_mlp1   = (const float*)d_in[18];
  A.w_end1   = (const float*)d_in[19]; A.b_end1   = (const float*)d_in[20];
  A.w_lin1   = (const float*)d_in[21]; A.b_lin1   = (const float*)d_in[22];
  A.gamma1   = (const float*)d_in[23]; A.beta1    = (const float*)d_in[24];
  A.HCOL = HCOL; A.flags = flags;
  A.out_all  = (float*)d_out;
  A.out_hrow = (float*)d_out + 5234688;
  A.out_hcol = (float*)d_out + 5308416;

  seq_kernel<<<192, NT, 0, stream>>>(A);
}

// Round 3
// 2644.267 us; speedup vs baseline: 1.0884x; 1.0238x over previous
//
#include <hip/hip_runtime.h>
#include <hip/hip_bf16.h>

#define NT 512
typedef unsigned short u16;
typedef unsigned long long u64;

__device__ __forceinline__ u16 tobf(float x) {
  union { __hip_bfloat16 h; u16 u; } cv;
  cv.h = __float2bfloat16(x);
  return cv.u;
}
__device__ __forceinline__ float frombf(u16 u) {
  return __uint_as_float(((unsigned)u) << 16);
}
__device__ __forceinline__ float sigf(float x) {
  return __builtin_amdgcn_rcpf(1.f + __builtin_amdgcn_exp2f(-1.4426950408889634f * x));
}
__device__ __forceinline__ float tanh_fast(float x) {
  return 1.f - 2.f * __builtin_amdgcn_rcpf(1.f + __builtin_amdgcn_exp2f(2.8853900817779268f * x));
}
// wave-local LDS ordering: waits this wave's ds ops, blocks compiler motion.
__device__ __forceinline__ void lds_fence() {
  asm volatile("s_waitcnt lgkmcnt(0)" ::: "memory");
  __builtin_amdgcn_sched_barrier(0);
}
// block barrier WITHOUT vmcnt(0) drain (LDS ordering only). Global stores drift.
__device__ __forceinline__ void bar_light() {
  asm volatile("s_waitcnt lgkmcnt(0)" ::: "memory");
  __builtin_amdgcn_s_barrier();
  asm volatile("" ::: "memory");
}

struct SeqArgs {
  const float* input;
  const float* nv1_0; const float* nv2_0; const float* nv1_1; const float* nv2_1;
  const float* w_start0; const float* b_start0; const float* w_mlp0; const float* b_mlp0;
  const float* w_end0;   const float* b_end0;   const float* w_lin0; const float* b_lin0;
  const float* gamma0;   const float* beta0;
  const float* w_start1; const float* b_start1; const float* w_mlp1; const float* b_mlp1;
  const float* w_end1;   const float* b_end1;   const float* w_lin1; const float* b_lin1;
  const float* gamma1;   const float* beta1;
  u64*   HCOL2;  // ws ring [16][192][192] of {f32 val, u32 tag}
  int*   prog;   // ws [192*32] ints, stride 32: consumer progress (backpressure)
  float* out_all; float* out_hrow; float* out_hcol;
};

__global__ __launch_bounds__(NT, 2) void seq_kernel(SeqArgs A) {
  const int n = blockIdx.x, w = n >> 3, b = n & 7, tid = threadIdx.x;
  const int pred = (n + 184) % 192;   // n-8 mod 192
  const int succ = (n + 8) % 192;

  __shared__ __align__(16) float sCIN[768];     // [h_row | h_col | x(<=2ch)]
  __shared__ __align__(16) u16   sWS[64 * 132]; // conv weights bf16, row=ich*16+c
  __shared__ __align__(16) float sAT[4096];     // aT[w*64+v]
  __shared__ __align__(16) float sH[2][1024];   // h0 / h1 rows [c*64+v]
  __shared__ __align__(16) float sAbuf[4928];
  float* const sPart = sAbuf;          // [0..3071] pre-conv partials (P*16*64)
  float* const sG    = sAbuf;          // [0..2047]
  float* const sH2c  = sAbuf + 2048;   // [2048..3071] h2 rows (dead after G)
  float* const sE    = sAbuf + 2048;   // [2048..2431] (overwrites dead h2)
  float* const sY    = sAbuf;          // [0..1151]   (overwrites dead sG)
  float* const smWE  = sAbuf + 3072;   // 192
  float* const smBE  = sAbuf + 3264;   // 6
  float* const smWM  = sAbuf + 3328;   // 32*50 (stride 50: bank-conflict-free)

  for (int layer = 0; layer < 2; ++layer) {
    const int in_dim = 3 + layer;
    const int P = in_dim - 1;  // pre channels: h_row + x-channels
    const float* nv1    = layer ? A.nv1_1    : A.nv1_0;
    const float* nv2    = layer ? A.nv2_1    : A.nv2_0;
    const float* wstart = layer ? A.w_start1 : A.w_start0;
    const float* bs     = layer ? A.b_start1 : A.b_start0;
    const float* wm     = layer ? A.w_mlp1   : A.w_mlp0;
    const float* bm     = layer ? A.b_mlp1   : A.b_mlp0;
    const float* we     = layer ? A.w_end1   : A.w_end0;
    const float* be     = layer ? A.b_end1   : A.b_end0;
    const float* wl     = layer ? A.w_lin1   : A.w_lin0;
    const float* bl     = layer ? A.b_lin1   : A.b_lin0;
    const float* gm     = layer ? A.gamma1   : A.gamma0;
    const float* bt     = layer ? A.beta1    : A.beta0;

    // ---- layer init: adjacency (scores -> softmax -> sAT), weights, regs ----
    for (int idx = tid; idx < 4096; idx += NT) {
      int v = idx >> 6, ww = idx & 63;
      float s = 0.f;
      for (int j = 0; j < 40; ++j) s = fmaf(nv1[v*40 + j], nv2[j*64 + ww], s);
      sAbuf[idx] = fmaxf(s, 0.f);
    }
    __syncthreads();
    if (tid < 64) {
      const int v = tid;
      float m = -1e30f;
      for (int ww = 0; ww < 64; ++ww) m = fmaxf(m, sAbuf[v*64 + ww]);
      float s = 0.f;
      for (int ww = 0; ww < 64; ++ww) { float e = expf(sAbuf[v*64 + ww] - m); sAbuf[v*64 + ww] = e; s += e; }
      float inv = 1.f / s, rs = 1.f;
      for (int ww = 0; ww < 64; ++ww) rs += sAbuf[v*64 + ww] * inv;
      float irs = 1.f / rs;
      for (int ww = 0; ww < 64; ++ww) {
        float a = sAbuf[v*64 + ww] * inv + ((ww == v) ? 1.f : 0.f);
        sAT[ww*64 + v] = a * irs;
      }
    }
    __syncthreads();  // sAT ready; scores region dead
    for (int idx = tid; idx < 16*in_dim*132; idx += NT) {
      int row = idx / 132, k = idx - row*132;
      sWS[idx] = (k < 129) ? tobf(wstart[((row & 15)*in_dim + (row >> 4))*129 + k]) : (u16)0;
    }
    for (int idx = tid; idx < 1536; idx += NT) { int o = idx/48, c = idx - o*48; smWM[o*50 + c] = wm[idx]; }
    for (int idx = tid; idx < 192; idx += NT) smWE[idx] = we[idx];
    if (tid < 6) smBE[tid] = be[tid];
    for (int d = tid; d < 384; d += NT) sCIN[d] = 0.f;

    const int v_p = tid & 63;
    const int o0  = tid >> 6;         // wave id, 0..7
    const float bmv0 = bm[o0], bmv1 = bm[o0 + 8], bmv2 = bm[o0 + 16], bmv3 = bm[o0 + 24];
    float blv = 0.f, gmv = 1.f, btv = 0.f;
    if (tid < 384) blv = bl[(tid >= 192) ? tid - 192 : tid];
    if (tid < 192) { gmv = gm[tid]; btv = bt[tid]; }
    float bs_r[2];
    bs_r[0] = bs[tid >> 6];
    bs_r[1] = bs[(tid >> 6) + 8];
    __syncthreads();

    // ---- conv+assemble of pre channels (x must already be in sCIN[384..]) ----
    auto pre_conv = [&]() {
      const int nslots = P << 8;
      for (int s = tid; s < nslots; s += NT) {
        const int cidx = s >> 4;
        const int p = cidx >> 4, c = cidx & 15;
        const int vg = s & 15;
        const int ich = (p == 0) ? 0 : (p + 1);
        const float* xin = ((p == 0) ? &sCIN[0] : &sCIN[384 + (p-1)*192]) + vg*4;
        const u16* wrow = &sWS[(ich*16 + c)*132];
        float a0 = 0.f, a1 = 0.f, a2 = 0.f, a3 = 0.f;
        float4 xc = *(const float4*)xin;
        for (int k4 = 0; k4 < 128; k4 += 4) {
          ushort4 wu = *(const ushort4*)(wrow + k4);
          float w0 = frombf(wu.x), w1 = frombf(wu.y), w2 = frombf(wu.z), w3 = frombf(wu.w);
          float4 xn = *(const float4*)(xin + k4 + 4);
          a0 = fmaf(w3, xc.w, fmaf(w2, xc.z, fmaf(w1, xc.y, fmaf(w0, xc.x, a0))));
          a1 = fmaf(w3, xn.x, fmaf(w2, xc.w, fmaf(w1, xc.z, fmaf(w0, xc.y, a1))));
          a2 = fmaf(w3, xn.y, fmaf(w2, xn.x, fmaf(w1, xc.w, fmaf(w0, xc.z, a2))));
          a3 = fmaf(w3, xn.z, fmaf(w2, xn.y, fmaf(w1, xn.x, fmaf(w0, xc.w, a3))));
          xc = xn;
        }
        float wk = frombf(wrow[128]);
        a0 = fmaf(wk, xc.x, a0); a1 = fmaf(wk, xc.y, a1);
        a2 = fmaf(wk, xc.z, a2); a3 = fmaf(wk, xc.w, a3);
        *(float4*)&sPart[cidx*64 + vg*4] = make_float4(a0, a1, a2, a3);
      }
      bar_light();
      {
        const int c0 = tid >> 6, v = tid & 63;
        float sum0 = bs_r[0], sum1 = bs_r[1];
        for (int p = 0; p < P; ++p) {
          sum0 += sPart[(p*16 + c0     )*64 + v];
          sum1 += sPart[(p*16 + c0 + 8 )*64 + v];
        }
        sH[0][ c0      *64 + v] = sum0;
        sH[0][(c0 + 8 )*64 + v] = sum1;
      }
      bar_light();
    };

    // ---- t=0 staging: x(0) direct from global ----
    {
      if (layer == 0) {
        int o = 0 - w;
        if (o >= 0 && o < 48) {
          const float* xr = A.input + (((size_t)(b*24 + w)*48 + o)*192);
          for (int d = tid; d < 192; d += NT) sCIN[384 + d] = xr[d];
        } else {
          for (int d = tid; d < 192; d += NT) sCIN[384 + d] = 0.f;
        }
      } else {
        const float* xr = A.out_all + ((size_t)n*71 + 0)*384;
        for (int d = tid; d < 384; d += NT) sCIN[384 + d] = xr[d];
      }
      bar_light();
      pre_conv();
    }

    for (int t = 0; t < 71; ++t) {
      const int S = layer*71 + t;

      // ---- x(t+1) prefetch into registers (latency overlaps whole step) ----
      float xpa = 0.f, xpb = 0.f;
      if (t < 70 && tid < 192) {
        if (layer == 0) {
          int o = (t + 1) - w;
          if (o >= 0 && o < 48)
            xpa = A.input[(((size_t)(b*24 + w)*48 + o)*192) + tid];
        } else {
          const float* xr = A.out_all + ((size_t)n*71 + (t+1))*384;
          xpa = xr[tid];
          xpb = xr[192 + tid];
        }
      }

      // ---- dependent path: per-lane tagged poll (single round-trip) ----
      if (t > 0) {
        if (tid < 192) {
          const u64* src = &A.HCOL2[((size_t)((S-1) & 15)*192 + pred)*192 + tid];
          u64 v;
          do {
            v = __hip_atomic_load(src, __ATOMIC_RELAXED, __HIP_MEMORY_SCOPE_AGENT);
          } while ((unsigned)(v >> 32) != (unsigned)S);
          sCIN[192 + tid] = __uint_as_float((unsigned)v);
        } else if (tid == 256 && S >= 16) {
          // backpressure: slot S&15 holds step S-16; its consumer posted prog>=S-15
          while (__hip_atomic_load(&A.prog[succ*32], __ATOMIC_RELAXED, __HIP_MEMORY_SCOPE_AGENT) < S - 15)
            __builtin_amdgcn_s_sleep(2);
        }
        bar_light();  // Bp
        if (tid == 0)
          __hip_atomic_store(&A.prog[n*32], S, __ATOMIC_RELAXED, __HIP_MEMORY_SCOPE_AGENT);
      } else if (S >= 16) {  // t==0, layer 1: still must respect ring reuse
        if (tid == 256) {
          while (__hip_atomic_load(&A.prog[succ*32], __ATOMIC_RELAXED, __HIP_MEMORY_SCOPE_AGENT) < S - 15)
            __builtin_amdgcn_s_sleep(2);
        }
        // no barrier needed: spin wave joins at B3; k1 stores happen after B7.
      }

      // ---- phase A (wave-local): h_col conv -> prop1 -> prop2 ----
      {
        const int c = tid >> 5, vg2 = tid & 31;
        const int vbase = c*64 + vg2*2;
        const float* xin = &sCIN[192 + vg2*2];
        const u16* wrow = &sWS[(16 + c)*132];
        float a0 = sH[0][vbase], a1 = sH[0][vbase + 1];
        float2 xc = *(const float2*)xin;
        for (int k2 = 0; k2 < 128; k2 += 2) {
          ushort2 wu = *(const ushort2*)(wrow + k2);
          float w0 = frombf(wu.x), w1 = frombf(wu.y);
          float2 xn = *(const float2*)(xin + k2 + 2);
          a0 = fmaf(w1, xc.y, fmaf(w0, xc.x, a0));
          a1 = fmaf(w1, xn.x, fmaf(w0, xc.y, a1));
          xc = xn;
        }
        float wk = frombf(wrow[128]);
        a0 = fmaf(wk, xc.x, a0); a1 = fmaf(wk, xc.y, a1);
        sH[0][vbase] = a0; sH[0][vbase + 1] = a1;
      }
      lds_fence();
      {
        const int c0 = o0 * 2;   // this wave's 2 rows
        float pa0 = 0.f, pa1 = 0.f;
        for (int w4 = 0; w4 < 64; w4 += 4) {
          float a0v = sAT[(w4+0)*64 + v_p];
          float a1v = sAT[(w4+1)*64 + v_p];
          float a2v = sAT[(w4+2)*64 + v_p];
          float a3v = sAT[(w4+3)*64 + v_p];
          float4 h0v = *(const float4*)&sH[0][ c0      *64 + w4];
          float4 h1v = *(const float4*)&sH[0][(c0 + 1 )*64 + w4];
          pa0 = fmaf(h0v.x, a0v, pa0); pa0 = fmaf(h0v.y, a1v, pa0);
          pa0 = fmaf(h0v.z, a2v, pa0); pa0 = fmaf(h0v.w, a3v, pa0);
          pa1 = fmaf(h1v.x, a0v, pa1); pa1 = fmaf(h1v.y, a1v, pa1);
          pa1 = fmaf(h1v.z, a2v, pa1); pa1 = fmaf(h1v.w, a3v, pa1);
        }
        float h0a = sH[0][ c0      *64 + v_p];
        float h0b = sH[0][(c0 + 1 )*64 + v_p];
        sH[1][ c0      *64 + v_p] = fmaf(0.95f, pa0, 0.05f * h0a);
        sH[1][(c0 + 1 )*64 + v_p] = fmaf(0.95f, pa1, 0.05f * h0b);
        lds_fence();
        float pb0 = 0.f, pb1 = 0.f;
        for (int w4 = 0; w4 < 64; w4 += 4) {
          float a0v = sAT[(w4+0)*64 + v_p];
          float a1v = sAT[(w4+1)*64 + v_p];
          float a2v = sAT[(w4+2)*64 + v_p];
          float a3v = sAT[(w4+3)*64 + v_p];
          float4 h0v = *(const float4*)&sH[1][ c0      *64 + w4];
          float4 h1v = *(const float4*)&sH[1][(c0 + 1 )*64 + w4];
          pb0 = fmaf(h0v.x, a0v, pb0); pb0 = fmaf(h0v.y, a1v, pb0);
          pb0 = fmaf(h0v.z, a2v, pb0); pb0 = fmaf(h0v.w, a3v, pb0);
          pb1 = fmaf(h1v.x, a0v, pb1); pb1 = fmaf(h1v.y, a1v, pb1);
          pb1 = fmaf(h1v.z, a2v, pb1); pb1 = fmaf(h1v.w, a3v, pb1);
        }
        sH2c[ c0      *64 + v_p] = fmaf(0.95f, pb0, 0.05f * h0a);
        sH2c[(c0 + 1 )*64 + v_p] = fmaf(0.95f, pb1, 0.05f * h0b);
      }
      bar_light();  // B3: h0/h1/h2 all ready

      // (g) G = bm + wm0 h0 + wm1 h1 + wm2 h2; exact GELU -> sG
      {
        float g0 = bmv0, g1 = bmv1, g2 = bmv2, g3 = bmv3;
#pragma unroll
        for (int c = 0; c < 16; ++c) {
          float h0v = sH[0][c*64 + v_p];
          float h1v = sH[1][c*64 + v_p];
          float h2v = sH2c[c*64 + v_p];
          g0 = fmaf(smWM[(o0     )*50 + c], h0v, fmaf(smWM[(o0     )*50 + 16 + c], h1v, fmaf(smWM[(o0     )*50 + 32 + c], h2v, g0)));
          g1 = fmaf(smWM[(o0 +  8)*50 + c], h0v, fmaf(smWM[(o0 +  8)*50 + 16 + c], h1v, fmaf(smWM[(o0 +  8)*50 + 32 + c], h2v, g1)));
          g2 = fmaf(smWM[(o0 + 16)*50 + c], h0v, fmaf(smWM[(o0 + 16)*50 + 16 + c], h1v, fmaf(smWM[(o0 + 16)*50 + 32 + c], h2v, g2)));
          g3 = fmaf(smWM[(o0 + 24)*50 + c], h0v, fmaf(smWM[(o0 + 24)*50 + 16 + c], h1v, fmaf(smWM[(o0 + 24)*50 + 32 + c], h2v, g3)));
        }
        g0 = 0.5f * g0 * (1.f + erff(g0 * 0.70710678118654752f));
        g1 = 0.5f * g1 * (1.f + erff(g1 * 0.70710678118654752f));
        g2 = 0.5f * g2 * (1.f + erff(g2 * 0.70710678118654752f));
        g3 = 0.5f * g3 * (1.f + erff(g3 * 0.70710678118654752f));
        sG[(o0     )*64 + v_p] = g0;
        sG[(o0 +  8)*64 + v_p] = g1;
        sG[(o0 + 16)*64 + v_p] = g2;
        sG[(o0 + 24)*64 + v_p] = g3;
      }
      bar_light();  // B4 (h2 region now dead -> sE may overwrite)

      // (h) E = be + we @ G
      for (int idx = tid; idx < 384; idx += NT) {
        int o2 = idx >> 6, v = idx & 63;
        float acc = smBE[o2];
        for (int c = 0; c < 32; ++c) acc = fmaf(smWE[o2*32 + c], sG[c*64 + v], acc);
        sE[idx] = acc;
      }
      bar_light();  // B5

      // (i) Y = bl + E @ wl^T : 384 threads, 3 rows each
      if (tid < 384) {
        const int d  = (tid >= 192) ? tid - 192 : tid;
        const int r0 = (tid >= 192) ? 3 : 0;
        const float4* wrow = (const float4*)(wl + d*64);
        float y0 = blv, y1 = blv, y2 = blv;
        for (int q = 0; q < 16; ++q) {
          float4 wv = wrow[q];
          float4 e0 = *(const float4*)&sE[(r0+0)*64 + q*4];
          float4 e1 = *(const float4*)&sE[(r0+1)*64 + q*4];
          float4 e2 = *(const float4*)&sE[(r0+2)*64 + q*4];
          y0 = fmaf(e0.x,wv.x, fmaf(e0.y,wv.y, fmaf(e0.z,wv.z, fmaf(e0.w,wv.w, y0))));
          y1 = fmaf(e1.x,wv.x, fmaf(e1.y,wv.y, fmaf(e1.z,wv.z, fmaf(e1.w,wv.w, y1))));
          y2 = fmaf(e2.x,wv.x, fmaf(e2.y,wv.y, fmaf(e2.z,wv.z, fmaf(e2.w,wv.w, y2))));
        }
        sY[(r0+0)*192 + d] = y0;
        sY[(r0+1)*192 + d] = y1;
        sY[(r0+2)*192 + d] = y2;
      }
      bar_light();  // B6

      // (j1) LN stats -> sH[1][0..13]
      if (tid < 192) {
        const int r = tid >> 5, l32 = tid & 31;
        float sm = 0.f, sq = 0.f;
#pragma unroll
        for (int m = 0; m < 6; ++m) {
          float v = sY[r*192 + l32 + 32*m];
          sm += v; sq = fmaf(v, v, sq);
        }
#pragma unroll
        for (int off = 16; off >= 1; off >>= 1) {
          sm += __shfl_xor(sm, off);
          sq += __shfl_xor(sq, off);
        }
        if (l32 == 0) {
          float mu = sm * (1.f/192.f);
          float var = sq * (1.f/192.f) - mu*mu;
          sH[1][r] = mu;
          sH[1][8 + r] = rsqrtf(fmaxf(var, 0.f) + 1e-5f);
        }
      }
      bar_light();  // B7

      float hcn = 0.f;
      // (k1) col gates -> hcn -> tagged 8B store (producer release, no drain)
      if (tid < 192) {
        const int d = tid;
        float y2 = fmaf((sY[2*192+d] - sH[1][2]) * sH[1][10], gmv, btv);
        float y3 = fmaf((sY[3*192+d] - sH[1][3]) * sH[1][11], gmv, btv);
        float y5 = fmaf((sY[5*192+d] - sH[1][5]) * sH[1][13], gmv, btv);
        float ugc = sigf(y2), ogc = sigf(y3), igc = tanh_fast(y5);
        float hc = sCIN[192 + d];
        hcn = tanh_fast(fmaf(ugc, igc, (1.f - ugc)*hc)) * ogc;
        u64 pk = ((u64)(unsigned)(S + 1) << 32) | (u64)__float_as_uint(hcn);
        __hip_atomic_store(&A.HCOL2[((size_t)(S & 15)*192 + n)*192 + d], pk,
                           __ATOMIC_RELAXED, __HIP_MEMORY_SCOPE_AGENT);
      }
      // (k2) row gates + outputs + x(t+1) publish (off critical path)
      if (tid < 192) {
        const int d = tid;
        float y0 = fmaf((sY[0*192+d] - sH[1][0]) * sH[1][8],  gmv, btv);
        float y1 = fmaf((sY[1*192+d] - sH[1][1]) * sH[1][9],  gmv, btv);
        float y4 = fmaf((sY[4*192+d] - sH[1][4]) * sH[1][12], gmv, btv);
        float ugr = sigf(y0), ogr = sigf(y1), igr = tanh_fast(y4);
        float hr = sCIN[d];
        float hrn = tanh_fast(fmaf(ugr, igr, (1.f - ugr)*hr)) * ogr;
        sCIN[d] = hrn;
        float* oa = A.out_all + ((size_t)n*71 + t)*384;
        if (layer == 0) { oa[d] = hrn; oa[192 + d] = hcn; }
        else           { oa[d] = hrn + sCIN[384 + d]; oa[192 + d] = hcn + sCIN[576 + d]; }
        if (t == 47 + w)
          A.out_hrow[(((size_t)b*2 + layer)*24 + w)*192 + d] = hrn;
        if (w == 23 && t >= 23)
          A.out_hcol[(((size_t)b*2 + layer)*48 + (t - 23))*192 + d] = hcn;
        // publish prefetched x(t+1) (same threads that read x(t) above: no hazard)
        if (t < 70) {
          sCIN[384 + d] = xpa;
          if (layer == 1) sCIN[576 + d] = xpb;
        }
      }
      bar_light();  // B9: h_row + x(t+1) visible
      if (t < 70) pre_conv();
    } // t
    __syncthreads();  // full barrier: drain out_all stores before next layer reads
  } // layer
}

extern "C" void kernel_launch(void* const* d_in, const int* in_sizes, int n_in,
                              void* d_out, int out_size, void* d_ws, size_t ws_size,
                              hipStream_t stream) {
  (void)in_sizes; (void)n_in; (void)out_size; (void)ws_size;
  char* ws = (char*)d_ws;
  int* prog  = (int*)ws;                   // 24,576 B (192 x 128B)
  u64* HCOL2 = (u64*)(ws + 24576);         // 16*192*192*8 = 4,718,592 B
  // total ws: 4,743,168 B (same as previous rounds)

  hipMemsetAsync(ws, 0, 24576 + 4718592, stream);  // zero prog + tags

  SeqArgs A;
  A.input    = (const float*)d_in[0];
  A.nv1_0    = (const float*)d_in[1];  A.nv2_0 = (const float*)d_in[2];
  A.w_start0 = (const float*)d_in[3];  A.b_start0 = (const float*)d_in[4];
  A.w_mlp0   = (const float*)d_in[5];  A.b_mlp0   = (const float*)d_in[6];
  A.w_end0   = (const float*)d_in[7];  A.b_end0   = (const float*)d_in[8];
  A.w_lin0   = (const float*)d_in[9];  A.b_lin0   = (const float*)d_in[10];
  A.gamma0   = (const float*)d_in[11]; A.beta0    = (const float*)d_in[12];
  A.nv1_1    = (const float*)d_in[13]; A.nv2_1 = (const float*)d_in[14];
  A.w_start1 = (const float*)d_in[15]; A.b_start1 = (const float*)d_in[16];
  A.w_mlp1   = (const float*)d_in[17]; A.b_mlp1   = (const float*)d_in[18];
  A.w_end1   = (const float*)d_in[19]; A.b_end1   = (const float*)d_in[20];
  A.w_lin1   = (const float*)d_in[21]; A.b_lin1   = (const float*)d_in[22];
  A.gamma1   = (const float*)d_in[23]; A.beta1    = (const float*)d_in[24];
  A.HCOL2 = HCOL2; A.prog = prog;
  A.out_all  = (float*)d_out;
  A.out_hrow = (float*)d_out + 5234688;
  A.out_hcol = (float*)d_out + 5308416;

  seq_kernel<<<192, NT, 0, stream>>>(A);
}